// Round 1
// baseline (556.735 us; speedup 1.0000x reference)
//
#include <hip/hip_runtime.h>
#include <stdint.h>

// ReLU relaxation (alpha-CROWN style), N = 8192.
// Output (f32), flat: [conc_low (n)] [conc_up (n)] [A_low (n+1)^2] [A_up (n+1)^2]
// A_low/A_up are diagonal + (A_up) last row; everything else zero.
//
// The harness poisons the whole 537 MB output before every call, so the floor
// is one full write pass. rocprof round 0: the driver's fillBufferAligned does
// 537 MB in 345 us = 1.55 TB/s (WRITE_SIZE counter is 4x-inflated on gfx950 -
// gfx94x formula fallback), i.e. only ~25% of the 6.29 TB/s copy ceiling.
// So: ONE fused kernel, nontemporal float4 stores, zeros everywhere except the
// ~0.1% of 16B chunks that contain nonzero structure.

typedef float f32x4 __attribute__((ext_vector_type(4)));

struct NodeVals { float diag_low, diag_up, bias_up, conc_low, conc_up; };

__device__ __forceinline__ NodeVals node_vals(float l, float u, float a_raw) {
    NodeVals nv;
    float a = fminf(fmaxf(a_raw, 0.f), 1.f);
    bool active   = (u > 0.f) && (l >= 0.f);
    bool unstable = (u > 0.f) && (l < 0.f);
    float denom = u - l;
    float lam = u / ((denom == 0.f) ? 1.f : denom);
    nv.diag_low = active ? 1.f : (unstable ? a : 0.f);
    nv.diag_up  = active ? 1.f : (unstable ? lam : 0.f);
    nv.bias_up  = unstable ? (-lam * l) : 0.f;
    nv.conc_low = active ? l : (unstable ? (a * l) : 0.f);
    nv.conc_up  = (u > 0.f) ? u : 0.f;
    return nv;
}

template <uint32_t NP1>
__global__ __launch_bounds__(256) void fused_fill(
        const float* __restrict__ lower,
        const float* __restrict__ upper,
        const float* __restrict__ alphas,
        float* __restrict__ out) {
    constexpr uint32_t N    = NP1 - 1;
    constexpr size_t   NPSQ = (size_t)NP1 * NP1;
    constexpr size_t   CONC = 2 * (size_t)N;        // conc_low + conc_up elements
    constexpr size_t   T    = CONC + 2 * NPSQ;      // total output elements
    constexpr size_t   C4   = T / 4;                // full float4 chunks
    static_assert(CONC % 4 == 0, "conc region must be float4-aligned");
    static_assert(T % 4 == 2, "tail handling assumes 2 trailing elements");

    f32x4* __restrict__ out4 = (f32x4*)out;
    const size_t stride = (size_t)gridDim.x * blockDim.x;

    for (size_t j = (size_t)blockIdx.x * blockDim.x + threadIdx.x; j < C4; j += stride) {
        const size_t e0 = j * 4;
        f32x4 v = (f32x4){0.f, 0.f, 0.f, 0.f};

        if (e0 < CONC) {
            // Dense concrete-bounds region (N % 4 == 0, so chunks never straddle).
            if (e0 < (size_t)N) {
                const f32x4 l4 = *(const f32x4*)(lower  + e0);
                const f32x4 u4 = *(const f32x4*)(upper  + e0);
                const f32x4 a4 = *(const f32x4*)(alphas + e0);
                v[0] = node_vals(l4[0], u4[0], a4[0]).conc_low;
                v[1] = node_vals(l4[1], u4[1], a4[1]).conc_low;
                v[2] = node_vals(l4[2], u4[2], a4[2]).conc_low;
                v[3] = node_vals(l4[3], u4[3], a4[3]).conc_low;
            } else {
                const f32x4 u4 = *(const f32x4*)(upper + (e0 - N));
                v[0] = (u4[0] > 0.f) ? u4[0] : 0.f;
                v[1] = (u4[1] > 0.f) ? u4[1] : 0.f;
                v[2] = (u4[2] > 0.f) ? u4[2] : 0.f;
                v[3] = (u4[3] > 0.f) ? u4[3] : 0.f;
            }
        } else {
            // A_low / A_up region. One constant-divide per chunk (magic-mul).
            const size_t g = e0 - CONC;
            int      mat = (g >= NPSQ) ? 1 : 0;     // 0 = A_low, 1 = A_up
            uint32_t h   = (uint32_t)(mat ? (g - NPSQ) : g);  // h < NP1^2 < 2^27
            uint32_t r   = h / NP1;
            uint32_t c   = h - r * NP1;

            // Slow iff the chunk can contain a nonzero: wraps a row boundary
            // (covers matrix boundary + next-row diag), touches the diagonal,
            // or lies in A_up's last (bias) row.
            const bool slow = (c > (uint32_t)(NP1 - 4)) |
                              ((uint32_t)(r - c) <= 3u) |
                              ((mat != 0) & (r == N));
            if (slow) {
                int m_ = mat; uint32_t rr = r, cc = c;
                #pragma unroll
                for (int k = 0; k < 4; ++k) {
                    float val = 0.f;
                    if (rr == cc) {
                        if (rr == N) {
                            val = 1.f;                       // A_*[n,n]
                        } else {
                            NodeVals nv = node_vals(lower[rr], upper[rr], alphas[rr]);
                            val = m_ ? nv.diag_up : nv.diag_low;
                        }
                    } else if (m_ && rr == N) {              // A_up last row, cc < N
                        NodeVals nv = node_vals(lower[cc], upper[cc], alphas[cc]);
                        val = nv.bias_up;
                    }
                    v[k] = val;
                    // advance one element, handling row and matrix wrap
                    ++cc;
                    if (cc == NP1) { cc = 0; ++rr; if (rr == NP1) { rr = 0; m_ = 1; } }
                }
            }
        }
        __builtin_nontemporal_store(v, out4 + j);
    }

    // Tail: last 2 elements = A_up[n, n-1] (bias) and A_up[n, n] (= 1).
    if (blockIdx.x == 0 && threadIdx.x == 0) {
        NodeVals nv = node_vals(lower[N - 1], upper[N - 1], alphas[N - 1]);
        out[T - 2] = nv.bias_up;
        out[T - 1] = 1.f;
    }
}

// Correctness fallback for any n (never taken in the bench; scalar, runtime div).
__global__ void generic_fill(const float* __restrict__ lower,
                             const float* __restrict__ upper,
                             const float* __restrict__ alphas,
                             float* __restrict__ out, int n) {
    const uint32_t np1  = (uint32_t)n + 1;
    const size_t   npsq = (size_t)np1 * np1;
    const size_t   conc = 2 * (size_t)n;
    const size_t   T    = conc + 2 * npsq;
    const size_t stride = (size_t)gridDim.x * blockDim.x;
    for (size_t e = (size_t)blockIdx.x * blockDim.x + threadIdx.x; e < T; e += stride) {
        float val = 0.f;
        if (e < (size_t)n) {
            val = node_vals(lower[e], upper[e], alphas[e]).conc_low;
        } else if (e < conc) {
            size_t i = e - n;
            val = node_vals(lower[i], upper[i], alphas[i]).conc_up;
        } else {
            size_t g = e - conc;
            int mat = (g >= npsq) ? 1 : 0;
            size_t h = mat ? (g - npsq) : g;
            uint32_t r = (uint32_t)(h / np1);
            uint32_t c = (uint32_t)(h - (size_t)r * np1);
            if (r == c) {
                if (r == (uint32_t)n) val = 1.f;
                else {
                    NodeVals nv = node_vals(lower[r], upper[r], alphas[r]);
                    val = mat ? nv.diag_up : nv.diag_low;
                }
            } else if (mat && r == (uint32_t)n) {
                val = node_vals(lower[c], upper[c], alphas[c]).bias_up;
            }
        }
        out[e] = val;
    }
}

extern "C" void kernel_launch(void* const* d_in, const int* in_sizes, int n_in,
                              void* d_out, int out_size, void* d_ws, size_t ws_size,
                              hipStream_t stream) {
    const float* lower  = (const float*)d_in[0];
    const float* upper  = (const float*)d_in[1];
    const float* alphas = (const float*)d_in[2];
    float* out = (float*)d_out;
    const int n = in_sizes[0];

    if (n == 8192) {
        // 33.5M float4 chunks; 4096 blocks x 256 threads -> 32 grid-stride iters.
        fused_fill<8193><<<4096, 256, 0, stream>>>(lower, upper, alphas, out);
    } else {
        generic_fill<<<2048, 256, 0, stream>>>(lower, upper, alphas, out, n);
    }
}